// Round 1
// baseline (1168.605 us; speedup 1.0000x reference)
//
#include <hip/hip_runtime.h>

#define NUSERS 100000
#define NPOIS  50000
#define NN     150000
#define DD     128
#define EE     2000000
#define BB     1024

// ---------- wave-aggregated compaction allocator ----------
__device__ __forceinline__ int wave_alloc(int* ctr, bool pred) {
    unsigned long long m = __ballot(pred);
    if (m == 0ull) return -1;
    int lane = threadIdx.x & 63;
    int before = __popcll(m & ((1ull << lane) - 1ull));
    int leader = __ffsll((unsigned long long)m) - 1;
    int base = 0;
    if (pred && lane == leader) base = atomicAdd(ctr, __popcll(m));
    base = __shfl(base, leader, 64);
    return base + before;
}

// ---------- degree / dinv ----------
__global__ void k_deg(const int* __restrict__ dst, int* __restrict__ cnt) {
    int stride = gridDim.x * blockDim.x;
    for (int e = blockIdx.x * blockDim.x + threadIdx.x; e < EE; e += stride)
        atomicAdd(&cnt[dst[e]], 1);
}

__global__ void k_dinv(const int* __restrict__ cnt, float* __restrict__ dinv) {
    int i = blockIdx.x * blockDim.x + threadIdx.x;
    if (i < NN) dinv[i] = rsqrtf(1.0f + (float)cnt[i]);
}

// ---------- set marking / compaction ----------
__global__ void k_mark(const int* __restrict__ uidx, int* __restrict__ mask_s2,
                       int* __restrict__ mask_t2) {
    int b = blockIdx.x * blockDim.x + threadIdx.x;
    if (b < BB) { int u = uidx[b]; mask_s2[u] = 1; mask_t2[u] = 1; }
}

__global__ void k_scan_s2(const int* __restrict__ src, const int* __restrict__ dst,
                          const int* __restrict__ mask_s2, int* __restrict__ mask_t2,
                          int* __restrict__ eid2, int* __restrict__ ctr) {
    int stride = gridDim.x * blockDim.x;
    for (int e = blockIdx.x * blockDim.x + threadIdx.x; e < EE; e += stride) {
        bool hit = (mask_s2[dst[e]] != 0);
        int pos = wave_alloc(&ctr[3], hit);
        if (hit) { eid2[pos] = e; mask_t2[src[e]] = 1; }
    }
}

__global__ void k_scan_t2(const int* __restrict__ dst, const int* __restrict__ mask_t2,
                          int* __restrict__ eid1, int* __restrict__ ctr) {
    int stride = gridDim.x * blockDim.x;
    for (int e = blockIdx.x * blockDim.x + threadIdx.x; e < EE; e += stride) {
        bool hit = (mask_t2[dst[e]] != 0);
        int pos = wave_alloc(&ctr[2], hit);
        if (hit) eid1[pos] = e;
    }
}

__global__ void k_slots(const int* __restrict__ mask_s2, const int* __restrict__ mask_t2,
                        int* __restrict__ slot_s2, int* __restrict__ slot_t2,
                        int* __restrict__ rev_s2, int* __restrict__ rev_t2,
                        int* __restrict__ ctr) {
    int i = blockIdx.x * blockDim.x + threadIdx.x;
    bool t2 = (i < NN) && (mask_t2[i] != 0);
    int st = wave_alloc(&ctr[0], t2);
    if (t2) { slot_t2[i] = st; rev_t2[st] = i; }
    bool s2 = (i < NN) && (mask_s2[i] != 0);
    int ss = wave_alloc(&ctr[1], s2);
    if (s2) { slot_s2[i] = ss; rev_s2[ss] = i; }
}

// ---------- tiny: bpW1[c] = sum_k bp[k] * W1[k][c] ----------
__global__ void k_bpw1(const float* __restrict__ bp, const float* __restrict__ W1,
                       float* __restrict__ bpW1) {
    int c = threadIdx.x;
    float s = 0.f;
    for (int k = 0; k < 128; ++k) s = fmaf(bp[k], W1[k * 128 + c], s);
    bpW1[c] = s;
}

// ---------- generic fp32 GEMM: C[M x 128] = A[M x K] @ W[K x 128] (+bias) ----------
// block 256 = 8 row-groups x 32 col-groups; micro-tile 4x4; K % 64 == 0.
__global__ __launch_bounds__(256)
void gemm_k(const float* __restrict__ A, const float* __restrict__ W,
            const float* __restrict__ bias, float* __restrict__ C,
            int M, const int* __restrict__ Mdyn, int K)
{
    __shared__ float Ws[64][128];
    __shared__ float As[64][36];   // padded stride 36 floats: 16B-aligned, conflict-free reads
    const int tid = threadIdx.x;
    const int tx = tid & 31;       // col group: cols 4*tx .. 4*tx+3
    const int ty = tid >> 5;       // row group: rows 4*ty .. 4*ty+3
    if (Mdyn) M = *Mdyn;
    const int ntiles = (M + 31) >> 5;
    for (int tile = blockIdx.x; tile < ntiles; tile += gridDim.x) {
        const int row0 = tile << 5;
        float acc[4][4] = {{0.f,0.f,0.f,0.f},{0.f,0.f,0.f,0.f},
                           {0.f,0.f,0.f,0.f},{0.f,0.f,0.f,0.f}};
        for (int kc = 0; kc < K; kc += 64) {
            __syncthreads();
            // stage W chunk 64x128 (8192 floats, 8 x float4 per thread, coalesced)
            #pragma unroll
            for (int i = 0; i < 8; ++i) {
                int id4 = (tid + i * 256) << 2;
                int kk = id4 >> 7, cc = id4 & 127;
                *(float4*)&Ws[kk][cc] = *(const float4*)&W[(size_t)(kc + kk) * 128 + cc];
            }
            // stage A chunk transposed: 32 rows x 64 k (2 x float4 per thread)
            #pragma unroll
            for (int i = 0; i < 2; ++i) {
                int id4 = (tid + i * 256) << 2;
                int r = id4 >> 6, kk = id4 & 63;
                int row = row0 + r;
                float4 v = make_float4(0.f, 0.f, 0.f, 0.f);
                if (row < M) v = *(const float4*)&A[(size_t)row * K + kc + kk];
                As[kk + 0][r] = v.x; As[kk + 1][r] = v.y;
                As[kk + 2][r] = v.z; As[kk + 3][r] = v.w;
            }
            __syncthreads();
            #pragma unroll 16
            for (int kk = 0; kk < 64; ++kk) {
                const float4 a4 = *(const float4*)&As[kk][ty << 2];
                const float4 w4 = *(const float4*)&Ws[kk][tx << 2];
                acc[0][0] = fmaf(a4.x, w4.x, acc[0][0]);
                acc[0][1] = fmaf(a4.x, w4.y, acc[0][1]);
                acc[0][2] = fmaf(a4.x, w4.z, acc[0][2]);
                acc[0][3] = fmaf(a4.x, w4.w, acc[0][3]);
                acc[1][0] = fmaf(a4.y, w4.x, acc[1][0]);
                acc[1][1] = fmaf(a4.y, w4.y, acc[1][1]);
                acc[1][2] = fmaf(a4.y, w4.z, acc[1][2]);
                acc[1][3] = fmaf(a4.y, w4.w, acc[1][3]);
                acc[2][0] = fmaf(a4.z, w4.x, acc[2][0]);
                acc[2][1] = fmaf(a4.z, w4.y, acc[2][1]);
                acc[2][2] = fmaf(a4.z, w4.z, acc[2][2]);
                acc[2][3] = fmaf(a4.z, w4.w, acc[2][3]);
                acc[3][0] = fmaf(a4.w, w4.x, acc[3][0]);
                acc[3][1] = fmaf(a4.w, w4.y, acc[3][1]);
                acc[3][2] = fmaf(a4.w, w4.z, acc[3][2]);
                acc[3][3] = fmaf(a4.w, w4.w, acc[3][3]);
            }
        }
        float4 b4 = make_float4(0.f, 0.f, 0.f, 0.f);
        if (bias) b4 = *(const float4*)&bias[tx << 2];
        #pragma unroll
        for (int j = 0; j < 4; ++j) {
            int row = row0 + (ty << 2) + j;
            if (row < M) {
                float4 o;
                o.x = acc[j][0] + b4.x; o.y = acc[j][1] + b4.y;
                o.z = acc[j][2] + b4.z; o.w = acc[j][3] + b4.w;
                *(float4*)&C[(size_t)row * 128 + (tx << 2)] = o;
            }
        }
    }
}

// ---------- layer aggregation (pruned) ----------
__global__ void k_init_x1c(const int* __restrict__ ctr, const int* __restrict__ rev_t2,
                           const float* __restrict__ dinv, const float* __restrict__ h1,
                           const float* __restrict__ b1, float* __restrict__ x1c) {
    const int n = ctr[0] << 5;     // slots * 32 float4
    int stride = gridDim.x * blockDim.x;
    for (int i = blockIdx.x * blockDim.x + threadIdx.x; i < n; i += stride) {
        int slot = i >> 5, q = (i & 31) << 2;
        int node = rev_t2[slot];
        float di = dinv[node]; float dd = di * di;
        const float4 h = *(const float4*)&h1[((size_t)node << 7) + q];
        const float4 b = *(const float4*)&b1[q];
        float4 o;
        o.x = fmaf(dd, h.x, b.x); o.y = fmaf(dd, h.y, b.y);
        o.z = fmaf(dd, h.z, b.z); o.w = fmaf(dd, h.w, b.w);
        *(float4*)&x1c[((size_t)slot << 7) + q] = o;
    }
}

__global__ void k_agg1(const int* __restrict__ ctr, const int* __restrict__ eid1,
                       const int* __restrict__ src, const int* __restrict__ dst,
                       const int* __restrict__ slot_t2, const float* __restrict__ dinv,
                       const float* __restrict__ h1, float* __restrict__ x1c) {
    const int n = ctr[2] << 5;     // edges * 32 float4
    int stride = gridDim.x * blockDim.x;
    for (int i = blockIdx.x * blockDim.x + threadIdx.x; i < n; i += stride) {
        int j = i >> 5, q = (i & 31) << 2;
        int e = eid1[j];
        int s = src[e], d = dst[e];
        float wgt = dinv[s] * dinv[d];
        const float4 h = *(const float4*)&h1[((size_t)s << 7) + q];
        float* p = &x1c[((size_t)slot_t2[d] << 7) + q];
        atomicAdd(p + 0, wgt * h.x); atomicAdd(p + 1, wgt * h.y);
        atomicAdd(p + 2, wgt * h.z); atomicAdd(p + 3, wgt * h.w);
    }
}

__global__ void k_leaky(const int* __restrict__ nptr, float* __restrict__ buf) {
    const int n = (*nptr) << 5;    // rows * 32 float4
    int stride = gridDim.x * blockDim.x;
    for (int i = blockIdx.x * blockDim.x + threadIdx.x; i < n; i += stride) {
        float4 v = *(float4*)&buf[(size_t)i << 2];
        v.x = v.x >= 0.f ? v.x : 0.2f * v.x;
        v.y = v.y >= 0.f ? v.y : 0.2f * v.y;
        v.z = v.z >= 0.f ? v.z : 0.2f * v.z;
        v.w = v.w >= 0.f ? v.w : 0.2f * v.w;
        *(float4*)&buf[(size_t)i << 2] = v;
    }
}

__global__ void k_init_x2c(const int* __restrict__ ctr, const int* __restrict__ rev_s2,
                           const int* __restrict__ slot_t2, const float* __restrict__ dinv,
                           const float* __restrict__ h2c, const float* __restrict__ b2,
                           float* __restrict__ x2c) {
    const int n = ctr[1] << 5;
    int stride = gridDim.x * blockDim.x;
    for (int i = blockIdx.x * blockDim.x + threadIdx.x; i < n; i += stride) {
        int slot = i >> 5, q = (i & 31) << 2;
        int node = rev_s2[slot];
        float di = dinv[node]; float dd = di * di;
        const float4 h = *(const float4*)&h2c[((size_t)slot_t2[node] << 7) + q];
        const float4 b = *(const float4*)&b2[q];
        float4 o;
        o.x = fmaf(dd, h.x, b.x); o.y = fmaf(dd, h.y, b.y);
        o.z = fmaf(dd, h.z, b.z); o.w = fmaf(dd, h.w, b.w);
        *(float4*)&x2c[((size_t)slot << 7) + q] = o;
    }
}

__global__ void k_agg2(const int* __restrict__ ctr, const int* __restrict__ eid2,
                       const int* __restrict__ src, const int* __restrict__ dst,
                       const int* __restrict__ slot_s2, const int* __restrict__ slot_t2,
                       const float* __restrict__ dinv, const float* __restrict__ h2c,
                       float* __restrict__ x2c) {
    const int n = ctr[3] << 5;
    int stride = gridDim.x * blockDim.x;
    for (int i = blockIdx.x * blockDim.x + threadIdx.x; i < n; i += stride) {
        int j = i >> 5, q = (i & 31) << 2;
        int e = eid2[j];
        int s = src[e], d = dst[e];
        float wgt = dinv[s] * dinv[d];
        const float4 h = *(const float4*)&h2c[((size_t)slot_t2[s] << 7) + q];
        float* p = &x2c[((size_t)slot_s2[d] << 7) + q];
        atomicAdd(p + 0, wgt * h.x); atomicAdd(p + 1, wgt * h.y);
        atomicAdd(p + 2, wgt * h.z); atomicAdd(p + 3, wgt * h.w);
    }
}

__global__ void k_finalA(const int* __restrict__ uidx, const int* __restrict__ slot_s2,
                         const float* __restrict__ x2c, const float* __restrict__ user_table,
                         float* __restrict__ Atmp) {
    int i = blockIdx.x * blockDim.x + threadIdx.x;   // over BB*32 float4
    if (i < BB * 32) {
        int b = i >> 5, q = (i & 31) << 2;
        int u = uidx[b];
        const float4 xv = *(const float4*)&x2c[((size_t)slot_s2[u] << 7) + q];
        const float4 uv = *(const float4*)&user_table[((size_t)u << 7) + q];
        float4 o;
        o.x = xv.x + uv.x; o.y = xv.y + uv.y; o.z = xv.z + uv.z; o.w = xv.w + uv.w;
        *(float4*)&Atmp[((size_t)b << 7) + q] = o;
    }
}

extern "C" void kernel_launch(void* const* d_in, const int* in_sizes, int n_in,
                              void* d_out, int out_size, void* d_ws, size_t ws_size,
                              hipStream_t stream) {
    const int*   uidx    = (const int*)d_in[0];
    const float* poi     = (const float*)d_in[1];
    const int*   src     = (const int*)d_in[2];           // edge_index[0]
    const int*   dst     = ((const int*)d_in[2]) + EE;    // edge_index[1]
    const float* usert   = (const float*)d_in[3];
    const float* Wp      = (const float*)d_in[4];
    const float* bp      = (const float*)d_in[5];
    const float* W1      = (const float*)d_in[6];
    const float* b1      = (const float*)d_in[7];
    const float* W2      = (const float*)d_in[8];
    const float* b2      = (const float*)d_in[9];
    const float* Wf      = (const float*)d_in[10];
    const float* bf      = (const float*)d_in[11];
    float* out = (float*)d_out;

    // ---- workspace layout ----
    char* w = (char*)d_ws;
    size_t off = 0;
    auto alloc = [&](size_t bytes) -> void* {
        void* p = w + off;
        off = (off + bytes + 255) & ~(size_t)255;
        return p;
    };
    float* dinv    = (float*)alloc((size_t)NN * 4);
    int*   cnt     = (int*)  alloc((size_t)NN * 4);
    int*   mask_s2 = (int*)  alloc((size_t)NN * 4);
    int*   mask_t2 = (int*)  alloc((size_t)NN * 4);
    int*   slot_s2 = (int*)  alloc((size_t)NN * 4);
    int*   slot_t2 = (int*)  alloc((size_t)NN * 4);
    int*   rev_t2  = (int*)  alloc((size_t)NN * 4);
    int*   rev_s2  = (int*)  alloc((size_t)BB * 4);
    int*   ctr     = (int*)  alloc(256);
    int*   eid1    = (int*)  alloc((size_t)EE * 4);
    int*   eid2    = (int*)  alloc((size_t)EE * 4);
    float* WpW1    = (float*)alloc((size_t)320 * 128 * 4);
    float* bpW1    = (float*)alloc((size_t)128 * 4);
    float* h1      = (float*)alloc((size_t)NN * 128 * 4);   // reused as h2c after layer 1
    float* x1c     = (float*)alloc((size_t)NN * 128 * 4);
    float* x2c     = (float*)alloc((size_t)BB * 128 * 4);
    float* Atmp    = (float*)alloc((size_t)BB * 128 * 4);
    if (off > ws_size) return;   // workspace too small -> visible failure
    float* h2c = h1;

    // ---- zero the count/mask/counter regions (contiguous allocs) ----
    hipMemsetAsync(cnt, 0, (size_t)((char*)slot_s2 - (char*)cnt), stream);
    hipMemsetAsync(ctr, 0, 256, stream);

    // ---- degree / dinv ----
    k_deg <<<2048, 256, 0, stream>>>(dst, cnt);
    k_dinv<<<(NN + 255) / 256, 256, 0, stream>>>(cnt, dinv);

    // ---- set construction ----
    k_mark   <<<(BB + 255) / 256, 256, 0, stream>>>(uidx, mask_s2, mask_t2);
    k_scan_s2<<<2048, 256, 0, stream>>>(src, dst, mask_s2, mask_t2, eid2, ctr);
    k_scan_t2<<<2048, 256, 0, stream>>>(dst, mask_t2, eid1, ctr);
    k_slots  <<<(NN + 255) / 256, 256, 0, stream>>>(mask_s2, mask_t2, slot_s2, slot_t2,
                                                    rev_s2, rev_t2, ctr);

    // ---- fused weights: WpW1 = Wp @ W1, bpW1 = bp @ W1 ----
    gemm_k<<<10, 256, 0, stream>>>(Wp, W1, nullptr, WpW1, 320, nullptr, 128);
    k_bpw1<<<1, 128, 0, stream>>>(bp, W1, bpW1);

    // ---- h1 for all nodes ----
    gemm_k<<<(NUSERS + 31) / 32, 256, 0, stream>>>(usert, W1, nullptr, h1, NUSERS, nullptr, 128);
    gemm_k<<<(NPOIS + 31) / 32, 256, 0, stream>>>(poi, WpW1, bpW1, h1 + (size_t)NUSERS * 128,
                                                  NPOIS, nullptr, 320);

    // ---- layer 1 at T2 ----
    k_init_x1c<<<512, 256, 0, stream>>>(ctr, rev_t2, dinv, h1, b1, x1c);
    k_agg1    <<<2048, 256, 0, stream>>>(ctr, eid1, src, dst, slot_t2, dinv, h1, x1c);
    k_leaky   <<<512, 256, 0, stream>>>(ctr + 0, x1c);

    // ---- h2 at T2 (compact GEMM, dynamic M), writes into h1 buffer ----
    gemm_k<<<1024, 256, 0, stream>>>(x1c, W2, nullptr, h2c, 0, ctr + 0, 128);

    // ---- layer 2 at S2 ----
    k_init_x2c<<<128, 256, 0, stream>>>(ctr, rev_s2, slot_t2, dinv, h2c, b2, x2c);
    k_agg2    <<<512, 256, 0, stream>>>(ctr, eid2, src, dst, slot_s2, slot_t2, dinv, h2c, x2c);
    k_leaky   <<<16, 256, 0, stream>>>(ctr + 1, x2c);

    // ---- final: out = (x2[user] + user_table[user]) @ Wf + bf ----
    k_finalA<<<(BB * 32 + 255) / 256, 256, 0, stream>>>(uidx, slot_s2, x2c, usert, Atmp);
    gemm_k  <<<(BB + 31) / 32, 256, 0, stream>>>(Atmp, Wf, bf, out, BB, nullptr, 128);
}

// Round 2
// 682.641 us; speedup vs baseline: 1.7119x; 1.7119x over previous
//
#include <hip/hip_runtime.h>

#define NUSERS 100000
#define NPOIS  50000
#define NN     150000
#define DD     128
#define EE     2000000
#define BB     1024

#define CH_IPT 16
#define CH_BLK 256
#define CHUNK  (CH_IPT * CH_BLK)   // 4096 items per block-chunk

// ---------- degree / dinv ----------
__global__ void k_deg(const int* __restrict__ dst, int* __restrict__ cnt) {
    int stride = gridDim.x * blockDim.x;
    for (int e = blockIdx.x * blockDim.x + threadIdx.x; e < EE; e += stride)
        atomicAdd(&cnt[dst[e]], 1);
}

__global__ void k_dinv(const int* __restrict__ cnt, float* __restrict__ dinv) {
    int i = blockIdx.x * blockDim.x + threadIdx.x;
    if (i < NN) dinv[i] = rsqrtf(1.0f + (float)cnt[i]);
}

// ---------- set marking ----------
__global__ void k_mark(const int* __restrict__ uidx, int* __restrict__ mask_s2,
                       int* __restrict__ mask_t2) {
    int b = blockIdx.x * blockDim.x + threadIdx.x;
    if (b < BB) { int u = uidx[b]; mask_s2[u] = 1; mask_t2[u] = 1; }
}

// ---------- block-aggregated edge compaction ----------
// One block per 4096-edge chunk; exactly ONE global atomic per chunk.
__global__ __launch_bounds__(256)
void k_scan_s2(const int* __restrict__ src, const int* __restrict__ dst,
               const int* __restrict__ mask_s2, int* __restrict__ mask_t2,
               int* __restrict__ eid2, int* __restrict__ ctr) {
    __shared__ int s_wcnt[4];
    __shared__ int s_base;
    const int tid = threadIdx.x;
    const int lane = tid & 63;
    const int wid = tid >> 6;
    const int nch = (EE + CHUNK - 1) / CHUNK;
    for (int c = blockIdx.x; c < nch; c += gridDim.x) {
        const int e0 = c * CHUNK;
        unsigned hitbits = 0;
        int wcnt = 0;
        #pragma unroll
        for (int i = 0; i < CH_IPT; ++i) {
            int e = e0 + i * CH_BLK + tid;
            bool h = (e < EE) && (mask_s2[dst[e]] != 0);
            unsigned long long m = __ballot(h);
            if (h) hitbits |= (1u << i);
            wcnt += __popcll(m);
        }
        if (lane == 0) s_wcnt[wid] = wcnt;
        __syncthreads();
        if (tid == 0) {
            int tot = s_wcnt[0] + s_wcnt[1] + s_wcnt[2] + s_wcnt[3];
            s_base = atomicAdd(&ctr[3], tot);
        }
        __syncthreads();
        int off = s_base;
        for (int w = 0; w < wid; ++w) off += s_wcnt[w];
        #pragma unroll
        for (int i = 0; i < CH_IPT; ++i) {
            unsigned long long m = __ballot((hitbits >> i) & 1);
            if ((hitbits >> i) & 1) {
                int e = e0 + i * CH_BLK + tid;
                int before = __popcll(m & ((1ull << lane) - 1ull));
                eid2[off + before] = e;
                mask_t2[src[e]] = 1;
            }
            off += __popcll(m);
        }
        __syncthreads();
    }
}

__global__ __launch_bounds__(256)
void k_scan_t2(const int* __restrict__ dst, const int* __restrict__ mask_t2,
               int* __restrict__ eid1, int* __restrict__ ctr) {
    __shared__ int s_wcnt[4];
    __shared__ int s_base;
    const int tid = threadIdx.x;
    const int lane = tid & 63;
    const int wid = tid >> 6;
    const int nch = (EE + CHUNK - 1) / CHUNK;
    for (int c = blockIdx.x; c < nch; c += gridDim.x) {
        const int e0 = c * CHUNK;
        unsigned hitbits = 0;
        int wcnt = 0;
        #pragma unroll
        for (int i = 0; i < CH_IPT; ++i) {
            int e = e0 + i * CH_BLK + tid;
            bool h = (e < EE) && (mask_t2[dst[e]] != 0);
            unsigned long long m = __ballot(h);
            if (h) hitbits |= (1u << i);
            wcnt += __popcll(m);
        }
        if (lane == 0) s_wcnt[wid] = wcnt;
        __syncthreads();
        if (tid == 0) {
            int tot = s_wcnt[0] + s_wcnt[1] + s_wcnt[2] + s_wcnt[3];
            s_base = atomicAdd(&ctr[2], tot);
        }
        __syncthreads();
        int off = s_base;
        for (int w = 0; w < wid; ++w) off += s_wcnt[w];
        #pragma unroll
        for (int i = 0; i < CH_IPT; ++i) {
            unsigned long long m = __ballot((hitbits >> i) & 1);
            if ((hitbits >> i) & 1) {
                int e = e0 + i * CH_BLK + tid;
                int before = __popcll(m & ((1ull << lane) - 1ull));
                eid1[off + before] = e;
            }
            off += __popcll(m);
        }
        __syncthreads();
    }
}

// ---------- block-aggregated slot assignment ----------
__global__ __launch_bounds__(256)
void k_slots(const int* __restrict__ mask_s2, const int* __restrict__ mask_t2,
             int* __restrict__ slot_s2, int* __restrict__ slot_t2,
             int* __restrict__ rev_s2, int* __restrict__ rev_t2,
             int* __restrict__ ctr) {
    __shared__ int s_wcnt_t[4], s_wcnt_s[4];
    __shared__ int s_base_t, s_base_s;
    const int tid = threadIdx.x;
    const int lane = tid & 63;
    const int wid = tid >> 6;
    const int nch = (NN + CHUNK - 1) / CHUNK;
    for (int c = blockIdx.x; c < nch; c += gridDim.x) {
        const int n0 = c * CHUNK;
        unsigned hbits_t = 0, hbits_s = 0;
        int wt = 0, ws = 0;
        #pragma unroll
        for (int i = 0; i < CH_IPT; ++i) {
            int n = n0 + i * CH_BLK + tid;
            bool inb = (n < NN);
            bool ht = inb && (mask_t2[n] != 0);
            bool hs = inb && (mask_s2[n] != 0);
            unsigned long long mt = __ballot(ht);
            unsigned long long ms = __ballot(hs);
            if (ht) hbits_t |= (1u << i);
            if (hs) hbits_s |= (1u << i);
            wt += __popcll(mt); ws += __popcll(ms);
        }
        if (lane == 0) { s_wcnt_t[wid] = wt; s_wcnt_s[wid] = ws; }
        __syncthreads();
        if (tid == 0) s_base_t = atomicAdd(&ctr[0], s_wcnt_t[0]+s_wcnt_t[1]+s_wcnt_t[2]+s_wcnt_t[3]);
        if (tid == 1) s_base_s = atomicAdd(&ctr[1], s_wcnt_s[0]+s_wcnt_s[1]+s_wcnt_s[2]+s_wcnt_s[3]);
        __syncthreads();
        int off_t = s_base_t, off_s = s_base_s;
        for (int w = 0; w < wid; ++w) { off_t += s_wcnt_t[w]; off_s += s_wcnt_s[w]; }
        #pragma unroll
        for (int i = 0; i < CH_IPT; ++i) {
            unsigned long long mt = __ballot((hbits_t >> i) & 1);
            unsigned long long ms = __ballot((hbits_s >> i) & 1);
            int n = n0 + i * CH_BLK + tid;
            if ((hbits_t >> i) & 1) {
                int p = off_t + __popcll(mt & ((1ull << lane) - 1ull));
                slot_t2[n] = p; rev_t2[p] = n;
            }
            if ((hbits_s >> i) & 1) {
                int p = off_s + __popcll(ms & ((1ull << lane) - 1ull));
                slot_s2[n] = p; rev_s2[p] = n;
            }
            off_t += __popcll(mt); off_s += __popcll(ms);
        }
        __syncthreads();
    }
}

// ---------- tiny: bpW1[c] = sum_k bp[k] * W1[k][c] ----------
__global__ void k_bpw1(const float* __restrict__ bp, const float* __restrict__ W1,
                       float* __restrict__ bpW1) {
    int c = threadIdx.x;
    float s = 0.f;
    for (int k = 0; k < 128; ++k) s = fmaf(bp[k], W1[k * 128 + c], s);
    bpW1[c] = s;
}

// ---------- generic fp32 GEMM: C[M x 128] = A[M x K] @ W[K x 128] (+bias) ----------
__global__ __launch_bounds__(256)
void gemm_k(const float* __restrict__ A, const float* __restrict__ W,
            const float* __restrict__ bias, float* __restrict__ C,
            int M, const int* __restrict__ Mdyn, int K)
{
    __shared__ float Ws[64][128];
    __shared__ float As[64][36];
    const int tid = threadIdx.x;
    const int tx = tid & 31;
    const int ty = tid >> 5;
    if (Mdyn) M = *Mdyn;
    const int ntiles = (M + 31) >> 5;
    for (int tile = blockIdx.x; tile < ntiles; tile += gridDim.x) {
        const int row0 = tile << 5;
        float acc[4][4] = {{0.f,0.f,0.f,0.f},{0.f,0.f,0.f,0.f},
                           {0.f,0.f,0.f,0.f},{0.f,0.f,0.f,0.f}};
        for (int kc = 0; kc < K; kc += 64) {
            __syncthreads();
            #pragma unroll
            for (int i = 0; i < 8; ++i) {
                int id4 = (tid + i * 256) << 2;
                int kk = id4 >> 7, cc = id4 & 127;
                *(float4*)&Ws[kk][cc] = *(const float4*)&W[(size_t)(kc + kk) * 128 + cc];
            }
            #pragma unroll
            for (int i = 0; i < 2; ++i) {
                int id4 = (tid + i * 256) << 2;
                int r = id4 >> 6, kk = id4 & 63;
                int row = row0 + r;
                float4 v = make_float4(0.f, 0.f, 0.f, 0.f);
                if (row < M) v = *(const float4*)&A[(size_t)row * K + kc + kk];
                As[kk + 0][r] = v.x; As[kk + 1][r] = v.y;
                As[kk + 2][r] = v.z; As[kk + 3][r] = v.w;
            }
            __syncthreads();
            #pragma unroll 16
            for (int kk = 0; kk < 64; ++kk) {
                const float4 a4 = *(const float4*)&As[kk][ty << 2];
                const float4 w4 = *(const float4*)&Ws[kk][tx << 2];
                acc[0][0] = fmaf(a4.x, w4.x, acc[0][0]);
                acc[0][1] = fmaf(a4.x, w4.y, acc[0][1]);
                acc[0][2] = fmaf(a4.x, w4.z, acc[0][2]);
                acc[0][3] = fmaf(a4.x, w4.w, acc[0][3]);
                acc[1][0] = fmaf(a4.y, w4.x, acc[1][0]);
                acc[1][1] = fmaf(a4.y, w4.y, acc[1][1]);
                acc[1][2] = fmaf(a4.y, w4.z, acc[1][2]);
                acc[1][3] = fmaf(a4.y, w4.w, acc[1][3]);
                acc[2][0] = fmaf(a4.z, w4.x, acc[2][0]);
                acc[2][1] = fmaf(a4.z, w4.y, acc[2][1]);
                acc[2][2] = fmaf(a4.z, w4.z, acc[2][2]);
                acc[2][3] = fmaf(a4.z, w4.w, acc[2][3]);
                acc[3][0] = fmaf(a4.w, w4.x, acc[3][0]);
                acc[3][1] = fmaf(a4.w, w4.y, acc[3][1]);
                acc[3][2] = fmaf(a4.w, w4.z, acc[3][2]);
                acc[3][3] = fmaf(a4.w, w4.w, acc[3][3]);
            }
        }
        float4 b4 = make_float4(0.f, 0.f, 0.f, 0.f);
        if (bias) b4 = *(const float4*)&bias[tx << 2];
        #pragma unroll
        for (int j = 0; j < 4; ++j) {
            int row = row0 + (ty << 2) + j;
            if (row < M) {
                float4 o;
                o.x = acc[j][0] + b4.x; o.y = acc[j][1] + b4.y;
                o.z = acc[j][2] + b4.z; o.w = acc[j][3] + b4.w;
                *(float4*)&C[(size_t)row * 128 + (tx << 2)] = o;
            }
        }
    }
}

// ---------- layer aggregation (pruned) ----------
__global__ void k_init_x1c(const int* __restrict__ ctr, const int* __restrict__ rev_t2,
                           const float* __restrict__ dinv, const float* __restrict__ h1,
                           const float* __restrict__ b1, float* __restrict__ x1c) {
    const int n = ctr[0] << 5;
    int stride = gridDim.x * blockDim.x;
    for (int i = blockIdx.x * blockDim.x + threadIdx.x; i < n; i += stride) {
        int slot = i >> 5, q = (i & 31) << 2;
        int node = rev_t2[slot];
        float di = dinv[node]; float dd = di * di;
        const float4 h = *(const float4*)&h1[((size_t)node << 7) + q];
        const float4 b = *(const float4*)&b1[q];
        float4 o;
        o.x = fmaf(dd, h.x, b.x); o.y = fmaf(dd, h.y, b.y);
        o.z = fmaf(dd, h.z, b.z); o.w = fmaf(dd, h.w, b.w);
        *(float4*)&x1c[((size_t)slot << 7) + q] = o;
    }
}

__global__ void k_agg1(const int* __restrict__ ctr, const int* __restrict__ eid1,
                       const int* __restrict__ src, const int* __restrict__ dst,
                       const int* __restrict__ slot_t2, const float* __restrict__ dinv,
                       const float* __restrict__ h1, float* __restrict__ x1c) {
    const int n = ctr[2] << 5;
    int stride = gridDim.x * blockDim.x;
    for (int i = blockIdx.x * blockDim.x + threadIdx.x; i < n; i += stride) {
        int j = i >> 5, q = (i & 31) << 2;
        int e = eid1[j];
        int s = src[e], d = dst[e];
        float wgt = dinv[s] * dinv[d];
        const float4 h = *(const float4*)&h1[((size_t)s << 7) + q];
        float* p = &x1c[((size_t)slot_t2[d] << 7) + q];
        atomicAdd(p + 0, wgt * h.x); atomicAdd(p + 1, wgt * h.y);
        atomicAdd(p + 2, wgt * h.z); atomicAdd(p + 3, wgt * h.w);
    }
}

__global__ void k_leaky(const int* __restrict__ nptr, float* __restrict__ buf) {
    const int n = (*nptr) << 5;
    int stride = gridDim.x * blockDim.x;
    for (int i = blockIdx.x * blockDim.x + threadIdx.x; i < n; i += stride) {
        float4 v = *(float4*)&buf[(size_t)i << 2];
        v.x = v.x >= 0.f ? v.x : 0.2f * v.x;
        v.y = v.y >= 0.f ? v.y : 0.2f * v.y;
        v.z = v.z >= 0.f ? v.z : 0.2f * v.z;
        v.w = v.w >= 0.f ? v.w : 0.2f * v.w;
        *(float4*)&buf[(size_t)i << 2] = v;
    }
}

__global__ void k_init_x2c(const int* __restrict__ ctr, const int* __restrict__ rev_s2,
                           const int* __restrict__ slot_t2, const float* __restrict__ dinv,
                           const float* __restrict__ h2c, const float* __restrict__ b2,
                           float* __restrict__ x2c) {
    const int n = ctr[1] << 5;
    int stride = gridDim.x * blockDim.x;
    for (int i = blockIdx.x * blockDim.x + threadIdx.x; i < n; i += stride) {
        int slot = i >> 5, q = (i & 31) << 2;
        int node = rev_s2[slot];
        float di = dinv[node]; float dd = di * di;
        const float4 h = *(const float4*)&h2c[((size_t)slot_t2[node] << 7) + q];
        const float4 b = *(const float4*)&b2[q];
        float4 o;
        o.x = fmaf(dd, h.x, b.x); o.y = fmaf(dd, h.y, b.y);
        o.z = fmaf(dd, h.z, b.z); o.w = fmaf(dd, h.w, b.w);
        *(float4*)&x2c[((size_t)slot << 7) + q] = o;
    }
}

__global__ void k_agg2(const int* __restrict__ ctr, const int* __restrict__ eid2,
                       const int* __restrict__ src, const int* __restrict__ dst,
                       const int* __restrict__ slot_s2, const int* __restrict__ slot_t2,
                       const float* __restrict__ dinv, const float* __restrict__ h2c,
                       float* __restrict__ x2c) {
    const int n = ctr[3] << 5;
    int stride = gridDim.x * blockDim.x;
    for (int i = blockIdx.x * blockDim.x + threadIdx.x; i < n; i += stride) {
        int j = i >> 5, q = (i & 31) << 2;
        int e = eid2[j];
        int s = src[e], d = dst[e];
        float wgt = dinv[s] * dinv[d];
        const float4 h = *(const float4*)&h2c[((size_t)slot_t2[s] << 7) + q];
        float* p = &x2c[((size_t)slot_s2[d] << 7) + q];
        atomicAdd(p + 0, wgt * h.x); atomicAdd(p + 1, wgt * h.y);
        atomicAdd(p + 2, wgt * h.z); atomicAdd(p + 3, wgt * h.w);
    }
}

__global__ void k_finalA(const int* __restrict__ uidx, const int* __restrict__ slot_s2,
                         const float* __restrict__ x2c, const float* __restrict__ user_table,
                         float* __restrict__ Atmp) {
    int i = blockIdx.x * blockDim.x + threadIdx.x;
    if (i < BB * 32) {
        int b = i >> 5, q = (i & 31) << 2;
        int u = uidx[b];
        const float4 xv = *(const float4*)&x2c[((size_t)slot_s2[u] << 7) + q];
        const float4 uv = *(const float4*)&user_table[((size_t)u << 7) + q];
        float4 o;
        o.x = xv.x + uv.x; o.y = xv.y + uv.y; o.z = xv.z + uv.z; o.w = xv.w + uv.w;
        *(float4*)&Atmp[((size_t)b << 7) + q] = o;
    }
}

extern "C" void kernel_launch(void* const* d_in, const int* in_sizes, int n_in,
                              void* d_out, int out_size, void* d_ws, size_t ws_size,
                              hipStream_t stream) {
    const int*   uidx    = (const int*)d_in[0];
    const float* poi     = (const float*)d_in[1];
    const int*   src     = (const int*)d_in[2];
    const int*   dst     = ((const int*)d_in[2]) + EE;
    const float* usert   = (const float*)d_in[3];
    const float* Wp      = (const float*)d_in[4];
    const float* bp      = (const float*)d_in[5];
    const float* W1      = (const float*)d_in[6];
    const float* b1      = (const float*)d_in[7];
    const float* W2      = (const float*)d_in[8];
    const float* b2      = (const float*)d_in[9];
    const float* Wf      = (const float*)d_in[10];
    const float* bf      = (const float*)d_in[11];
    float* out = (float*)d_out;

    char* w = (char*)d_ws;
    size_t off = 0;
    auto alloc = [&](size_t bytes) -> void* {
        void* p = w + off;
        off = (off + bytes + 255) & ~(size_t)255;
        return p;
    };
    float* dinv    = (float*)alloc((size_t)NN * 4);
    int*   cnt     = (int*)  alloc((size_t)NN * 4);
    int*   mask_s2 = (int*)  alloc((size_t)NN * 4);
    int*   mask_t2 = (int*)  alloc((size_t)NN * 4);
    int*   slot_s2 = (int*)  alloc((size_t)NN * 4);
    int*   slot_t2 = (int*)  alloc((size_t)NN * 4);
    int*   rev_t2  = (int*)  alloc((size_t)NN * 4);
    int*   rev_s2  = (int*)  alloc((size_t)BB * 4);
    int*   ctr     = (int*)  alloc(256);
    int*   eid1    = (int*)  alloc((size_t)EE * 4);
    int*   eid2    = (int*)  alloc((size_t)EE * 4);
    float* WpW1    = (float*)alloc((size_t)320 * 128 * 4);
    float* bpW1    = (float*)alloc((size_t)128 * 4);
    float* h1      = (float*)alloc((size_t)NN * 128 * 4);
    float* x1c     = (float*)alloc((size_t)NN * 128 * 4);
    float* x2c     = (float*)alloc((size_t)BB * 128 * 4);
    float* Atmp    = (float*)alloc((size_t)BB * 128 * 4);
    if (off > ws_size) return;
    float* h2c = h1;

    hipMemsetAsync(cnt, 0, (size_t)((char*)slot_s2 - (char*)cnt), stream);
    hipMemsetAsync(ctr, 0, 256, stream);

    k_deg <<<2048, 256, 0, stream>>>(dst, cnt);
    k_dinv<<<(NN + 255) / 256, 256, 0, stream>>>(cnt, dinv);

    k_mark   <<<(BB + 255) / 256, 256, 0, stream>>>(uidx, mask_s2, mask_t2);
    k_scan_s2<<<(EE + CHUNK - 1) / CHUNK, 256, 0, stream>>>(src, dst, mask_s2, mask_t2, eid2, ctr);
    k_scan_t2<<<(EE + CHUNK - 1) / CHUNK, 256, 0, stream>>>(dst, mask_t2, eid1, ctr);
    k_slots  <<<(NN + CHUNK - 1) / CHUNK, 256, 0, stream>>>(mask_s2, mask_t2, slot_s2, slot_t2,
                                                            rev_s2, rev_t2, ctr);

    gemm_k<<<10, 256, 0, stream>>>(Wp, W1, nullptr, WpW1, 320, nullptr, 128);
    k_bpw1<<<1, 128, 0, stream>>>(bp, W1, bpW1);

    gemm_k<<<(NUSERS + 31) / 32, 256, 0, stream>>>(usert, W1, nullptr, h1, NUSERS, nullptr, 128);
    gemm_k<<<(NPOIS + 31) / 32, 256, 0, stream>>>(poi, WpW1, bpW1, h1 + (size_t)NUSERS * 128,
                                                  NPOIS, nullptr, 320);

    k_init_x1c<<<512, 256, 0, stream>>>(ctr, rev_t2, dinv, h1, b1, x1c);
    k_agg1    <<<2048, 256, 0, stream>>>(ctr, eid1, src, dst, slot_t2, dinv, h1, x1c);
    k_leaky   <<<512, 256, 0, stream>>>(ctr + 0, x1c);

    gemm_k<<<1024, 256, 0, stream>>>(x1c, W2, nullptr, h2c, 0, ctr + 0, 128);

    k_init_x2c<<<128, 256, 0, stream>>>(ctr, rev_s2, slot_t2, dinv, h2c, b2, x2c);
    k_agg2    <<<512, 256, 0, stream>>>(ctr, eid2, src, dst, slot_s2, slot_t2, dinv, h2c, x2c);
    k_leaky   <<<16, 256, 0, stream>>>(ctr + 1, x2c);

    k_finalA<<<(BB * 32 + 255) / 256, 256, 0, stream>>>(uidx, slot_s2, x2c, usert, Atmp);
    gemm_k  <<<(BB + 31) / 32, 256, 0, stream>>>(Atmp, Wf, bf, out, BB, nullptr, 128);
}

// Round 3
// 401.504 us; speedup vs baseline: 2.9106x; 1.7002x over previous
//
#include <hip/hip_runtime.h>

#define NUSERS 100000
#define NPOIS  50000
#define NN     150000
#define DD     128
#define EE     2000000
#define BB     1024

#define CH_IPT 16
#define CH_BLK 256
#define CHUNK  (CH_IPT * CH_BLK)   // 4096 items per block-chunk

// ---------- set marking (user nodes) ----------
__global__ void k_mark(const int* __restrict__ uidx, int* __restrict__ mask_s2,
                       int* __restrict__ mask_t2) {
    int b = blockIdx.x * blockDim.x + threadIdx.x;
    if (b < BB) { int u = uidx[b]; mask_s2[u] = 1; mask_t2[u] = 1; }
}

// ---------- fused: degree count + T2 marking ----------
__global__ void k_deg_mark(const int* __restrict__ src, const int* __restrict__ dst,
                           const int* __restrict__ mask_s2,
                           int* __restrict__ cnt, int* __restrict__ mask_t2) {
    int stride = gridDim.x * blockDim.x;
    for (int e = blockIdx.x * blockDim.x + threadIdx.x; e < EE; e += stride) {
        int d = dst[e];
        atomicAdd(&cnt[d], 1);
        if (mask_s2[d]) mask_t2[src[e]] = 1;
    }
}

__global__ void k_dinv(const int* __restrict__ cnt, float* __restrict__ dinv) {
    int i = blockIdx.x * blockDim.x + threadIdx.x;
    if (i < NN) dinv[i] = rsqrtf(1.0f + (float)cnt[i]);
}

// ---------- block-aggregated slot assignment (2 atomics / 4096 nodes) ----------
__global__ __launch_bounds__(256)
void k_slots(const int* __restrict__ mask_s2, const int* __restrict__ mask_t2,
             int* __restrict__ slot_s2, int* __restrict__ slot_t2,
             int* __restrict__ rev_s2, int* __restrict__ rev_t2,
             int* __restrict__ ctr) {
    __shared__ int s_wcnt_t[4], s_wcnt_s[4];
    __shared__ int s_base_t, s_base_s;
    const int tid = threadIdx.x;
    const int lane = tid & 63;
    const int wid = tid >> 6;
    const int nch = (NN + CHUNK - 1) / CHUNK;
    for (int c = blockIdx.x; c < nch; c += gridDim.x) {
        const int n0 = c * CHUNK;
        unsigned hbits_t = 0, hbits_s = 0;
        int wt = 0, ws = 0;
        #pragma unroll
        for (int i = 0; i < CH_IPT; ++i) {
            int n = n0 + i * CH_BLK + tid;
            bool inb = (n < NN);
            bool ht = inb && (mask_t2[n] != 0);
            bool hs = inb && (mask_s2[n] != 0);
            unsigned long long mt = __ballot(ht);
            unsigned long long ms = __ballot(hs);
            if (ht) hbits_t |= (1u << i);
            if (hs) hbits_s |= (1u << i);
            wt += __popcll(mt); ws += __popcll(ms);
        }
        if (lane == 0) { s_wcnt_t[wid] = wt; s_wcnt_s[wid] = ws; }
        __syncthreads();
        if (tid == 0) s_base_t = atomicAdd(&ctr[0], s_wcnt_t[0]+s_wcnt_t[1]+s_wcnt_t[2]+s_wcnt_t[3]);
        if (tid == 1) s_base_s = atomicAdd(&ctr[1], s_wcnt_s[0]+s_wcnt_s[1]+s_wcnt_s[2]+s_wcnt_s[3]);
        __syncthreads();
        int off_t = s_base_t, off_s = s_base_s;
        for (int w = 0; w < wid; ++w) { off_t += s_wcnt_t[w]; off_s += s_wcnt_s[w]; }
        #pragma unroll
        for (int i = 0; i < CH_IPT; ++i) {
            unsigned long long mt = __ballot((hbits_t >> i) & 1);
            unsigned long long ms = __ballot((hbits_s >> i) & 1);
            int n = n0 + i * CH_BLK + tid;
            if ((hbits_t >> i) & 1) {
                int p = off_t + __popcll(mt & ((1ull << lane) - 1ull));
                slot_t2[n] = p; rev_t2[p] = n;
            }
            if ((hbits_s >> i) & 1) {
                int p = off_s + __popcll(ms & ((1ull << lane) - 1ull));
                slot_s2[n] = p; rev_s2[p] = n;
            }
            off_t += __popcll(mt); off_s += __popcll(ms);
        }
        __syncthreads();
    }
}

// ---------- CSR degree counting (both layers, one edge pass) ----------
__global__ void k_count(const int* __restrict__ dst,
                        const int* __restrict__ mask_s2, const int* __restrict__ mask_t2,
                        const int* __restrict__ slot_s2, const int* __restrict__ slot_t2,
                        int* __restrict__ deg1, int* __restrict__ deg2) {
    int stride = gridDim.x * blockDim.x;
    for (int e = blockIdx.x * blockDim.x + threadIdx.x; e < EE; e += stride) {
        int d = dst[e];
        if (mask_t2[d]) atomicAdd(&deg1[slot_t2[d]], 1);
        if (mask_s2[d]) atomicAdd(&deg2[slot_s2[d]], 1);
    }
}

// ---------- single-block exclusive scan (shfl wave scan, 4096/tile) ----------
__global__ __launch_bounds__(1024)
void k_scan_excl(const int* __restrict__ nptr, const int* __restrict__ deg,
                 int* __restrict__ ptr, int* __restrict__ cur) {
    __shared__ int wsum[16];
    __shared__ int s_carry;
    const int tid = threadIdx.x;
    const int lane = tid & 63, wid = tid >> 6;
    const int n = *nptr;
    if (tid == 0) s_carry = 0;
    __syncthreads();
    for (int base = 0; base < n; base += 4096) {
        int i0 = base + tid * 4;
        int v[4];
        #pragma unroll
        for (int k = 0; k < 4; ++k) {
            int i = i0 + k;
            v[k] = (i < n) ? deg[i] : 0;
        }
        int tsum = v[0] + v[1] + v[2] + v[3];
        int x = tsum;
        #pragma unroll
        for (int s = 1; s < 64; s <<= 1) {
            int y = __shfl_up(x, s, 64);
            if (lane >= s) x += y;
        }
        if (lane == 63) wsum[wid] = x;
        __syncthreads();
        if (wid == 0) {
            int wv = (lane < 16) ? wsum[lane] : 0;
            #pragma unroll
            for (int s = 1; s < 16; s <<= 1) {
                int y = __shfl_up(wv, s, 64);
                if (lane >= s) wv += y;
            }
            if (lane < 16) wsum[lane] = wv;
        }
        __syncthreads();
        int carry = s_carry;
        int woff = (wid > 0) ? wsum[wid - 1] : 0;
        int excl = carry + woff + (x - tsum);
        #pragma unroll
        for (int k = 0; k < 4; ++k) {
            int i = i0 + k;
            if (i < n) { ptr[i] = excl; cur[i] = excl; }
            excl += v[k];
        }
        __syncthreads();
        if (tid == 0) s_carry = carry + wsum[15];
        __syncthreads();
    }
}

// ---------- CSR scatter (both layers, one edge pass; int atomics on cursors) ----------
__global__ void k_scatter(const int* __restrict__ src, const int* __restrict__ dst,
                          const int* __restrict__ mask_s2, const int* __restrict__ mask_t2,
                          const int* __restrict__ slot_s2, const int* __restrict__ slot_t2,
                          int* __restrict__ cur1, int* __restrict__ cur2,
                          int* __restrict__ csr1, int* __restrict__ csr2) {
    int stride = gridDim.x * blockDim.x;
    for (int e = blockIdx.x * blockDim.x + threadIdx.x; e < EE; e += stride) {
        int d = dst[e];
        bool t = (mask_t2[d] != 0);
        bool s2 = (mask_s2[d] != 0);
        if (t | s2) {
            int s = src[e];
            if (t)  { int p = atomicAdd(&cur1[slot_t2[d]], 1); csr1[p] = s; }
            if (s2) { int p = atomicAdd(&cur2[slot_s2[d]], 1); csr2[p] = s; }
        }
    }
}

// ---------- tiny: bpW1[c] = sum_k bp[k] * W1[k][c] ----------
__global__ void k_bpw1(const float* __restrict__ bp, const float* __restrict__ W1,
                       float* __restrict__ bpW1) {
    int c = threadIdx.x;
    float s = 0.f;
    for (int k = 0; k < 128; ++k) s = fmaf(bp[k], W1[k * 128 + c], s);
    bpW1[c] = s;
}

// ---------- generic fp32 GEMM: C[M x 128] = A[M x K] @ W[K x 128] (+bias) ----------
__global__ __launch_bounds__(256)
void gemm_k(const float* __restrict__ A, const float* __restrict__ W,
            const float* __restrict__ bias, float* __restrict__ C,
            int M, const int* __restrict__ Mdyn, int K)
{
    __shared__ float Ws[64][128];
    __shared__ float As[64][36];
    const int tid = threadIdx.x;
    const int tx = tid & 31;
    const int ty = tid >> 5;
    if (Mdyn) M = *Mdyn;
    const int ntiles = (M + 31) >> 5;
    for (int tile = blockIdx.x; tile < ntiles; tile += gridDim.x) {
        const int row0 = tile << 5;
        float acc[4][4] = {{0.f,0.f,0.f,0.f},{0.f,0.f,0.f,0.f},
                           {0.f,0.f,0.f,0.f},{0.f,0.f,0.f,0.f}};
        for (int kc = 0; kc < K; kc += 64) {
            __syncthreads();
            #pragma unroll
            for (int i = 0; i < 8; ++i) {
                int id4 = (tid + i * 256) << 2;
                int kk = id4 >> 7, cc = id4 & 127;
                *(float4*)&Ws[kk][cc] = *(const float4*)&W[(size_t)(kc + kk) * 128 + cc];
            }
            #pragma unroll
            for (int i = 0; i < 2; ++i) {
                int id4 = (tid + i * 256) << 2;
                int r = id4 >> 6, kk = id4 & 63;
                int row = row0 + r;
                float4 v = make_float4(0.f, 0.f, 0.f, 0.f);
                if (row < M) v = *(const float4*)&A[(size_t)row * K + kc + kk];
                As[kk + 0][r] = v.x; As[kk + 1][r] = v.y;
                As[kk + 2][r] = v.z; As[kk + 3][r] = v.w;
            }
            __syncthreads();
            #pragma unroll 16
            for (int kk = 0; kk < 64; ++kk) {
                const float4 a4 = *(const float4*)&As[kk][ty << 2];
                const float4 w4 = *(const float4*)&Ws[kk][tx << 2];
                acc[0][0] = fmaf(a4.x, w4.x, acc[0][0]);
                acc[0][1] = fmaf(a4.x, w4.y, acc[0][1]);
                acc[0][2] = fmaf(a4.x, w4.z, acc[0][2]);
                acc[0][3] = fmaf(a4.x, w4.w, acc[0][3]);
                acc[1][0] = fmaf(a4.y, w4.x, acc[1][0]);
                acc[1][1] = fmaf(a4.y, w4.y, acc[1][1]);
                acc[1][2] = fmaf(a4.y, w4.z, acc[1][2]);
                acc[1][3] = fmaf(a4.y, w4.w, acc[1][3]);
                acc[2][0] = fmaf(a4.z, w4.x, acc[2][0]);
                acc[2][1] = fmaf(a4.z, w4.y, acc[2][1]);
                acc[2][2] = fmaf(a4.z, w4.z, acc[2][2]);
                acc[2][3] = fmaf(a4.z, w4.w, acc[2][3]);
                acc[3][0] = fmaf(a4.w, w4.x, acc[3][0]);
                acc[3][1] = fmaf(a4.w, w4.y, acc[3][1]);
                acc[3][2] = fmaf(a4.w, w4.z, acc[3][2]);
                acc[3][3] = fmaf(a4.w, w4.w, acc[3][3]);
            }
        }
        float4 b4 = make_float4(0.f, 0.f, 0.f, 0.f);
        if (bias) b4 = *(const float4*)&bias[tx << 2];
        #pragma unroll
        for (int j = 0; j < 4; ++j) {
            int row = row0 + (ty << 2) + j;
            if (row < M) {
                float4 o;
                o.x = acc[j][0] + b4.x; o.y = acc[j][1] + b4.y;
                o.z = acc[j][2] + b4.z; o.w = acc[j][3] + b4.w;
                *(float4*)&C[(size_t)row * 128 + (tx << 2)] = o;
            }
        }
    }
}

// ---------- layer-1 aggregation: one wave per T2 slot, registers only ----------
__global__ __launch_bounds__(256)
void k_agg1(const int* __restrict__ ctr, const int* __restrict__ rev_t2,
            const int* __restrict__ ptr1, const int* __restrict__ deg1,
            const int* __restrict__ csr1, const float* __restrict__ dinv,
            const float* __restrict__ h1, const float* __restrict__ b1,
            float* __restrict__ x1c) {
    const int nt2 = ctr[0];
    const int lane = threadIdx.x & 63;
    const int col = lane << 1;
    const int wslot0 = (blockIdx.x * blockDim.x + threadIdx.x) >> 6;
    const int nwaves = (gridDim.x * blockDim.x) >> 6;
    for (int slot = wslot0; slot < nt2; slot += nwaves) {
        int node = rev_t2[slot];
        float dn = dinv[node];
        float dd = dn * dn;
        float2 acc = *(const float2*)&h1[((size_t)node << 7) + col];
        const float2 bb = *(const float2*)&b1[col];
        acc.x = fmaf(dd, acc.x, bb.x);
        acc.y = fmaf(dd, acc.y, bb.y);
        int j = ptr1[slot], jend = j + deg1[slot];
        for (; j < jend; ++j) {
            int s = csr1[j];
            float w = dinv[s] * dn;
            const float2 h = *(const float2*)&h1[((size_t)s << 7) + col];
            acc.x = fmaf(w, h.x, acc.x);
            acc.y = fmaf(w, h.y, acc.y);
        }
        acc.x = acc.x >= 0.f ? acc.x : 0.2f * acc.x;   // fused leaky
        acc.y = acc.y >= 0.f ? acc.y : 0.2f * acc.y;
        *(float2*)&x1c[((size_t)slot << 7) + col] = acc;
    }
}

// ---------- layer-2 aggregation: one wave per S2 slot ----------
__global__ __launch_bounds__(256)
void k_agg2(const int* __restrict__ ctr, const int* __restrict__ rev_s2,
            const int* __restrict__ ptr2, const int* __restrict__ deg2,
            const int* __restrict__ csr2, const int* __restrict__ slot_t2,
            const float* __restrict__ dinv, const float* __restrict__ h2c,
            const float* __restrict__ b2, float* __restrict__ x2c) {
    const int ns2 = ctr[1];
    const int lane = threadIdx.x & 63;
    const int col = lane << 1;
    const int wslot0 = (blockIdx.x * blockDim.x + threadIdx.x) >> 6;
    const int nwaves = (gridDim.x * blockDim.x) >> 6;
    for (int slot = wslot0; slot < ns2; slot += nwaves) {
        int node = rev_s2[slot];
        float dn = dinv[node];
        float dd = dn * dn;
        float2 acc = *(const float2*)&h2c[((size_t)slot_t2[node] << 7) + col];
        const float2 bb = *(const float2*)&b2[col];
        acc.x = fmaf(dd, acc.x, bb.x);
        acc.y = fmaf(dd, acc.y, bb.y);
        int j = ptr2[slot], jend = j + deg2[slot];
        for (; j < jend; ++j) {
            int s = csr2[j];
            float w = dinv[s] * dn;
            const float2 h = *(const float2*)&h2c[((size_t)slot_t2[s] << 7) + col];
            acc.x = fmaf(w, h.x, acc.x);
            acc.y = fmaf(w, h.y, acc.y);
        }
        acc.x = acc.x >= 0.f ? acc.x : 0.2f * acc.x;
        acc.y = acc.y >= 0.f ? acc.y : 0.2f * acc.y;
        *(float2*)&x2c[((size_t)slot << 7) + col] = acc;
    }
}

__global__ void k_finalA(const int* __restrict__ uidx, const int* __restrict__ slot_s2,
                         const float* __restrict__ x2c, const float* __restrict__ user_table,
                         float* __restrict__ Atmp) {
    int i = blockIdx.x * blockDim.x + threadIdx.x;
    if (i < BB * 32) {
        int b = i >> 5, q = (i & 31) << 2;
        int u = uidx[b];
        const float4 xv = *(const float4*)&x2c[((size_t)slot_s2[u] << 7) + q];
        const float4 uv = *(const float4*)&user_table[((size_t)u << 7) + q];
        float4 o;
        o.x = xv.x + uv.x; o.y = xv.y + uv.y; o.z = xv.z + uv.z; o.w = xv.w + uv.w;
        *(float4*)&Atmp[((size_t)b << 7) + q] = o;
    }
}

extern "C" void kernel_launch(void* const* d_in, const int* in_sizes, int n_in,
                              void* d_out, int out_size, void* d_ws, size_t ws_size,
                              hipStream_t stream) {
    const int*   uidx    = (const int*)d_in[0];
    const float* poi     = (const float*)d_in[1];
    const int*   src     = (const int*)d_in[2];
    const int*   dst     = ((const int*)d_in[2]) + EE;
    const float* usert   = (const float*)d_in[3];
    const float* Wp      = (const float*)d_in[4];
    const float* bp      = (const float*)d_in[5];
    const float* W1      = (const float*)d_in[6];
    const float* b1      = (const float*)d_in[7];
    const float* W2      = (const float*)d_in[8];
    const float* b2      = (const float*)d_in[9];
    const float* Wf      = (const float*)d_in[10];
    const float* bf      = (const float*)d_in[11];
    float* out = (float*)d_out;

    char* w = (char*)d_ws;
    size_t off = 0;
    auto alloc = [&](size_t bytes) -> void* {
        void* p = w + off;
        off = (off + bytes + 255) & ~(size_t)255;
        return p;
    };
    float* dinv    = (float*)alloc((size_t)NN * 4);
    int*   cnt     = (int*)  alloc((size_t)NN * 4);   // reused as deg1
    int*   mask_s2 = (int*)  alloc((size_t)NN * 4);
    int*   mask_t2 = (int*)  alloc((size_t)NN * 4);
    int*   slot_s2 = (int*)  alloc((size_t)NN * 4);
    int*   slot_t2 = (int*)  alloc((size_t)NN * 4);
    int*   rev_t2  = (int*)  alloc((size_t)NN * 4);
    int*   rev_s2  = (int*)  alloc((size_t)BB * 4);
    int*   ptr1    = (int*)  alloc((size_t)(NN + 1) * 4);
    int*   cur1    = (int*)  alloc((size_t)(NN + 1) * 4);
    int*   deg2    = (int*)  alloc((size_t)(BB + 2) * 4);
    int*   ptr2    = (int*)  alloc((size_t)(BB + 2) * 4);
    int*   cur2    = (int*)  alloc((size_t)(BB + 2) * 4);
    int*   ctr     = (int*)  alloc(256);
    int*   csr1    = (int*)  alloc((size_t)EE * 4);
    int*   csr2    = (int*)  alloc((size_t)EE * 4);
    float* WpW1    = (float*)alloc((size_t)320 * 128 * 4);
    float* bpW1    = (float*)alloc((size_t)128 * 4);
    float* h1      = (float*)alloc((size_t)NN * 128 * 4);
    float* x1c     = (float*)alloc((size_t)NN * 128 * 4);
    float* x2c     = (float*)alloc((size_t)BB * 128 * 4);
    float* Atmp    = (float*)alloc((size_t)BB * 128 * 4);
    if (off > ws_size) return;
    float* h2c = h1;
    int* deg1 = cnt;

    // zero: cnt + masks (contiguous), small CSR bufs, counters
    hipMemsetAsync(cnt, 0, (size_t)((char*)slot_s2 - (char*)cnt), stream);
    hipMemsetAsync(deg2, 0, (size_t)(BB + 2) * 4, stream);
    hipMemsetAsync(ctr, 0, 256, stream);

    // marking + degree + dinv
    k_mark    <<<(BB + 255) / 256, 256, 0, stream>>>(uidx, mask_s2, mask_t2);
    k_deg_mark<<<2048, 256, 0, stream>>>(src, dst, mask_s2, cnt, mask_t2);
    k_dinv    <<<(NN + 255) / 256, 256, 0, stream>>>(cnt, dinv);

    // slot assignment
    k_slots<<<(NN + CHUNK - 1) / CHUNK, 256, 0, stream>>>(mask_s2, mask_t2, slot_s2, slot_t2,
                                                          rev_s2, rev_t2, ctr);

    // CSR build: deg1 reuses cnt (re-zero), count, scan, scatter
    hipMemsetAsync(deg1, 0, (size_t)NN * 4, stream);
    k_count  <<<2048, 256, 0, stream>>>(dst, mask_s2, mask_t2, slot_s2, slot_t2, deg1, deg2);
    k_scan_excl<<<1, 1024, 0, stream>>>(ctr + 0, deg1, ptr1, cur1);
    k_scan_excl<<<1, 1024, 0, stream>>>(ctr + 1, deg2, ptr2, cur2);
    k_scatter<<<2048, 256, 0, stream>>>(src, dst, mask_s2, mask_t2, slot_s2, slot_t2,
                                        cur1, cur2, csr1, csr2);

    // fused weights: WpW1 = Wp @ W1, bpW1 = bp @ W1
    gemm_k<<<10, 256, 0, stream>>>(Wp, W1, nullptr, WpW1, 320, nullptr, 128);
    k_bpw1<<<1, 128, 0, stream>>>(bp, W1, bpW1);

    // h1 for all nodes
    gemm_k<<<(NUSERS + 31) / 32, 256, 0, stream>>>(usert, W1, nullptr, h1, NUSERS, nullptr, 128);
    gemm_k<<<(NPOIS + 31) / 32, 256, 0, stream>>>(poi, WpW1, bpW1, h1 + (size_t)NUSERS * 128,
                                                  NPOIS, nullptr, 320);

    // layer 1 at T2 (fused init + aggregate + bias + leaky)
    k_agg1<<<2048, 256, 0, stream>>>(ctr, rev_t2, ptr1, deg1, csr1, dinv, h1, b1, x1c);

    // h2 at T2 (compact GEMM, dynamic M)
    gemm_k<<<1024, 256, 0, stream>>>(x1c, W2, nullptr, h2c, 0, ctr + 0, 128);

    // layer 2 at S2 (fused)
    k_agg2<<<256, 256, 0, stream>>>(ctr, rev_s2, ptr2, deg2, csr2, slot_t2, dinv, h2c, b2, x2c);

    // final: out = (x2[user] + user_table[user]) @ Wf + bf
    k_finalA<<<(BB * 32 + 255) / 256, 256, 0, stream>>>(uidx, slot_s2, x2c, usert, Atmp);
    gemm_k  <<<(BB + 31) / 32, 256, 0, stream>>>(Atmp, Wf, bf, out, BB, nullptr, 128);
}

// Round 4
// 367.323 us; speedup vs baseline: 3.1814x; 1.0931x over previous
//
#include <hip/hip_runtime.h>

#define NUSERS 100000
#define NPOIS  50000
#define NN     150000
#define DD     128
#define EE     2000000
#define BB     1024

#define CH_IPT 16
#define CH_BLK 256
#define CHUNK  (CH_IPT * CH_BLK)   // 4096 items per block-chunk

typedef __attribute__((ext_vector_type(8))) short short8;
typedef __attribute__((ext_vector_type(4))) float f32x4;
typedef unsigned short ushort_t;

__device__ __forceinline__ ushort_t f2bf(float x) {
    union { float f; unsigned u; } a; a.f = x;
    unsigned r = a.u + 0x7fffu + ((a.u >> 16) & 1u);   // round-to-nearest-even
    return (ushort_t)(r >> 16);
}
__device__ __forceinline__ float bf2f(ushort_t h) {
    union { unsigned u; float f; } a; a.u = ((unsigned)h) << 16;
    return a.f;
}

// ---------- set marking (user nodes) ----------
__global__ void k_mark(const int* __restrict__ uidx, int* __restrict__ mask_s2,
                       int* __restrict__ mask_t2) {
    int b = blockIdx.x * blockDim.x + threadIdx.x;
    if (b < BB) { int u = uidx[b]; mask_s2[u] = 1; mask_t2[u] = 1; }
}

// ---------- fused: degree count + T2 marking ----------
__global__ void k_deg_mark(const int* __restrict__ src, const int* __restrict__ dst,
                           const int* __restrict__ mask_s2,
                           int* __restrict__ cnt, int* __restrict__ mask_t2) {
    int stride = gridDim.x * blockDim.x;
    for (int e = blockIdx.x * blockDim.x + threadIdx.x; e < EE; e += stride) {
        int d = dst[e];
        atomicAdd(&cnt[d], 1);
        if (mask_s2[d]) mask_t2[src[e]] = 1;
    }
}

__global__ void k_dinv(const int* __restrict__ cnt, float* __restrict__ dinv) {
    int i = blockIdx.x * blockDim.x + threadIdx.x;
    if (i < NN) dinv[i] = rsqrtf(1.0f + (float)cnt[i]);
}

// ---------- block-aggregated slot assignment (2 atomics / 4096 nodes) ----------
__global__ __launch_bounds__(256)
void k_slots(const int* __restrict__ mask_s2, const int* __restrict__ mask_t2,
             int* __restrict__ slot_s2, int* __restrict__ slot_t2,
             int* __restrict__ rev_s2, int* __restrict__ rev_t2,
             int* __restrict__ ctr) {
    __shared__ int s_wcnt_t[4], s_wcnt_s[4];
    __shared__ int s_base_t, s_base_s;
    const int tid = threadIdx.x;
    const int lane = tid & 63;
    const int wid = tid >> 6;
    const int nch = (NN + CHUNK - 1) / CHUNK;
    for (int c = blockIdx.x; c < nch; c += gridDim.x) {
        const int n0 = c * CHUNK;
        unsigned hbits_t = 0, hbits_s = 0;
        int wt = 0, ws = 0;
        #pragma unroll
        for (int i = 0; i < CH_IPT; ++i) {
            int n = n0 + i * CH_BLK + tid;
            bool inb = (n < NN);
            bool ht = inb && (mask_t2[n] != 0);
            bool hs = inb && (mask_s2[n] != 0);
            unsigned long long mt = __ballot(ht);
            unsigned long long ms = __ballot(hs);
            if (ht) hbits_t |= (1u << i);
            if (hs) hbits_s |= (1u << i);
            wt += __popcll(mt); ws += __popcll(ms);
        }
        if (lane == 0) { s_wcnt_t[wid] = wt; s_wcnt_s[wid] = ws; }
        __syncthreads();
        if (tid == 0) s_base_t = atomicAdd(&ctr[0], s_wcnt_t[0]+s_wcnt_t[1]+s_wcnt_t[2]+s_wcnt_t[3]);
        if (tid == 1) s_base_s = atomicAdd(&ctr[1], s_wcnt_s[0]+s_wcnt_s[1]+s_wcnt_s[2]+s_wcnt_s[3]);
        __syncthreads();
        int off_t = s_base_t, off_s = s_base_s;
        for (int w = 0; w < wid; ++w) { off_t += s_wcnt_t[w]; off_s += s_wcnt_s[w]; }
        #pragma unroll
        for (int i = 0; i < CH_IPT; ++i) {
            unsigned long long mt = __ballot((hbits_t >> i) & 1);
            unsigned long long ms = __ballot((hbits_s >> i) & 1);
            int n = n0 + i * CH_BLK + tid;
            if ((hbits_t >> i) & 1) {
                int p = off_t + __popcll(mt & ((1ull << lane) - 1ull));
                slot_t2[n] = p; rev_t2[p] = n;
            }
            if ((hbits_s >> i) & 1) {
                int p = off_s + __popcll(ms & ((1ull << lane) - 1ull));
                slot_s2[n] = p; rev_s2[p] = n;
            }
            off_t += __popcll(mt); off_s += __popcll(ms);
        }
        __syncthreads();
    }
}

// ---------- dual exclusive scan over per-slot degrees (deg[i] = cnt[rev[i]]) ----------
__global__ __launch_bounds__(1024)
void k_scan2(const int* __restrict__ ctr, const int* __restrict__ rev_t2,
             const int* __restrict__ rev_s2, const int* __restrict__ cnt,
             int* __restrict__ ptr1, int* __restrict__ cur1,
             int* __restrict__ ptr2, int* __restrict__ cur2) {
    __shared__ int wsum[16];
    __shared__ int s_carry;
    const int which = blockIdx.x;
    const int n = ctr[which];
    const int* rev = which ? rev_s2 : rev_t2;
    int* ptr = which ? ptr2 : ptr1;
    int* cur = which ? cur2 : cur1;
    const int tid = threadIdx.x;
    const int lane = tid & 63, wid = tid >> 6;
    if (tid == 0) s_carry = 0;
    __syncthreads();
    for (int base = 0; base < n; base += 4096) {
        int i0 = base + tid * 4;
        int v[4];
        #pragma unroll
        for (int k = 0; k < 4; ++k) {
            int i = i0 + k;
            v[k] = (i < n) ? cnt[rev[i]] : 0;
        }
        int tsum = v[0] + v[1] + v[2] + v[3];
        int x = tsum;
        #pragma unroll
        for (int s = 1; s < 64; s <<= 1) {
            int y = __shfl_up(x, s, 64);
            if (lane >= s) x += y;
        }
        if (lane == 63) wsum[wid] = x;
        __syncthreads();
        if (wid == 0) {
            int wv = (lane < 16) ? wsum[lane] : 0;
            #pragma unroll
            for (int s = 1; s < 16; s <<= 1) {
                int y = __shfl_up(wv, s, 64);
                if (lane >= s) wv += y;
            }
            if (lane < 16) wsum[lane] = wv;
        }
        __syncthreads();
        int carry = s_carry;
        int woff = (wid > 0) ? wsum[wid - 1] : 0;
        int excl = carry + woff + (x - tsum);
        #pragma unroll
        for (int k = 0; k < 4; ++k) {
            int i = i0 + k;
            if (i < n) { ptr[i] = excl; cur[i] = excl; }
            excl += v[k];
        }
        __syncthreads();
        if (tid == 0) s_carry = carry + wsum[15];
        __syncthreads();
    }
}

// ---------- CSR scatter (both layers, one edge pass; int atomics on cursors) ----------
__global__ void k_scatter(const int* __restrict__ src, const int* __restrict__ dst,
                          const int* __restrict__ mask_s2, const int* __restrict__ mask_t2,
                          const int* __restrict__ slot_s2, const int* __restrict__ slot_t2,
                          int* __restrict__ cur1, int* __restrict__ cur2,
                          int* __restrict__ csr1, int* __restrict__ csr2) {
    int stride = gridDim.x * blockDim.x;
    for (int e = blockIdx.x * blockDim.x + threadIdx.x; e < EE; e += stride) {
        int d = dst[e];
        bool t = (mask_t2[d] != 0);
        bool s2 = (mask_s2[d] != 0);
        if (t | s2) {
            int s = src[e];
            if (t)  { int p = atomicAdd(&cur1[slot_t2[d]], 1); csr1[p] = s; }
            if (s2) { int p = atomicAdd(&cur2[slot_s2[d]], 1); csr2[p] = s; }
        }
    }
}

// ---------- W prep: split fp32 [K][128] into transposed bf16 hi/lo [128][K] ----------
__global__ void k_wprepT(const float* __restrict__ W, ushort_t* __restrict__ Th,
                         ushort_t* __restrict__ Tl, int K) {
    int i = blockIdx.x * blockDim.x + threadIdx.x;
    if (i >= K * 128) return;
    int k = i >> 7, n = i & 127;
    float x = W[i];
    ushort_t h = f2bf(x);
    ushort_t l = f2bf(x - bf2f(h));
    Th[n * K + k] = h; Tl[n * K + k] = l;
}

// ---------- tiny: bpW1[c] = sum_k bp[k] * W1[k][c] ----------
__global__ void k_bpw1(const float* __restrict__ bp, const float* __restrict__ W1,
                       float* __restrict__ bpW1) {
    int c = threadIdx.x;
    float s = 0.f;
    for (int k = 0; k < 128; ++k) s = fmaf(bp[k], W1[k * 128 + c], s);
    bpW1[c] = s;
}

// ---------- split-bf16 MFMA GEMM: C[M][128] = A[M][K] @ B[K][128] (+bias) ----------
// B supplied pre-split/transposed: BTh/BTl = bf16 [128 n][K k].
// Block 256 thr = 2x2 waves; tile 64 rows x 128 cols; K-step 64; K % 64 == 0.
// Split: C ~= Ahi*Bhi + Ahi*Blo + Alo*Bhi (lo*lo dropped, ~2^-18 rel).
// LDS XOR-swizzle byte ^= (row&7)<<4 on both A and B tiles (conflict-free reads).
__global__ __launch_bounds__(256)
void gemm_mfma(const float* __restrict__ A,
               const ushort_t* __restrict__ BTh, const ushort_t* __restrict__ BTl,
               const float* __restrict__ bias, float* __restrict__ C,
               int M, const int* __restrict__ Mdyn, int K)
{
    __shared__ ushort_t Bh[128 * 64], Bl[128 * 64];   // [n][k] 16KB each
    __shared__ ushort_t Ah[64 * 64],  Al[64 * 64];    // [r][k]  8KB each
    const int tid = threadIdx.x;
    const int wave = tid >> 6, lane = tid & 63;
    const int wr = wave >> 1, wc = wave & 1;
    const int lr = lane & 15, g = lane >> 4;
    if (Mdyn) M = *Mdyn;
    const int ntiles = (M + 63) >> 6;
    for (int tile = blockIdx.x; tile < ntiles; tile += gridDim.x) {
        const int row0 = tile << 6;
        f32x4 acc[2][4];
        #pragma unroll
        for (int a = 0; a < 2; ++a)
            #pragma unroll
            for (int b = 0; b < 4; ++b) acc[a][b] = (f32x4){0.f, 0.f, 0.f, 0.f};
        for (int kc = 0; kc < K; kc += 64) {
            __syncthreads();
            // stage B hi/lo: 128 n x 64 k, 16B chunks, swizzled
            #pragma unroll
            for (int i = 0; i < 4; ++i) {
                int c = tid + i * 256;            // 0..1023
                int n = c >> 3, kq = c & 7;
                size_t go = (size_t)n * K + kc + kq * 8;
                int boff = n * 128 + ((kq * 16) ^ ((n & 7) << 4));
                *(int4*)((char*)Bh + boff) = *(const int4*)&BTh[go];
                *(int4*)((char*)Bl + boff) = *(const int4*)&BTl[go];
            }
            // stage A: 64 r x 64 k fp32 -> bf16 hi/lo, swizzled
            #pragma unroll
            for (int i = 0; i < 4; ++i) {
                int c = tid + i * 256;
                int r = c >> 4, k4 = (c & 15) << 2;
                int row = row0 + r;
                float4 v = make_float4(0.f, 0.f, 0.f, 0.f);
                if (row < M) v = *(const float4*)&A[(size_t)row * K + kc + k4];
                ushort_t h0 = f2bf(v.x), h1 = f2bf(v.y), h2 = f2bf(v.z), h3 = f2bf(v.w);
                ushort_t l0 = f2bf(v.x - bf2f(h0)), l1 = f2bf(v.y - bf2f(h1));
                ushort_t l2 = f2bf(v.z - bf2f(h2)), l3 = f2bf(v.w - bf2f(h3));
                int aoff = r * 128 + ((k4 * 2) ^ ((r & 7) << 4));
                uint2 hw, lw;
                hw.x = (unsigned)h0 | ((unsigned)h1 << 16);
                hw.y = (unsigned)h2 | ((unsigned)h3 << 16);
                lw.x = (unsigned)l0 | ((unsigned)l1 << 16);
                lw.y = (unsigned)l2 | ((unsigned)l3 << 16);
                *(uint2*)((char*)Ah + aoff) = hw;
                *(uint2*)((char*)Al + aoff) = lw;
            }
            __syncthreads();
            #pragma unroll
            for (int kk2 = 0; kk2 < 2; ++kk2) {
                short8 afh[2], afl[2];
                #pragma unroll
                for (int rt = 0; rt < 2; ++rt) {
                    int ar = wr * 32 + rt * 16 + lr;
                    int off = ar * 128 + ((kk2 * 64 + g * 16) ^ ((ar & 7) << 4));
                    afh[rt] = *(short8*)((char*)Ah + off);
                    afl[rt] = *(short8*)((char*)Al + off);
                }
                #pragma unroll
                for (int ct = 0; ct < 4; ++ct) {
                    int bn = wc * 64 + ct * 16 + lr;
                    int off = bn * 128 + ((kk2 * 64 + g * 16) ^ ((bn & 7) << 4));
                    short8 bfh = *(short8*)((char*)Bh + off);
                    short8 bfl = *(short8*)((char*)Bl + off);
                    #pragma unroll
                    for (int rt = 0; rt < 2; ++rt) {
                        acc[rt][ct] = __builtin_amdgcn_mfma_f32_16x16x32_bf16(afh[rt], bfh, acc[rt][ct], 0, 0, 0);
                        acc[rt][ct] = __builtin_amdgcn_mfma_f32_16x16x32_bf16(afh[rt], bfl, acc[rt][ct], 0, 0, 0);
                        acc[rt][ct] = __builtin_amdgcn_mfma_f32_16x16x32_bf16(afl[rt], bfh, acc[rt][ct], 0, 0, 0);
                    }
                }
            }
        }
        // epilogue: C/D layout col = lane&15, row = (lane>>4)*4 + reg  [m89-verified]
        #pragma unroll
        for (int ct = 0; ct < 4; ++ct) {
            int col = wc * 64 + ct * 16 + lr;
            float bv = bias ? bias[col] : 0.f;
            #pragma unroll
            for (int rt = 0; rt < 2; ++rt) {
                #pragma unroll
                for (int v = 0; v < 4; ++v) {
                    int row = row0 + wr * 32 + rt * 16 + g * 4 + v;
                    if (row < M) C[(size_t)row * 128 + col] = acc[rt][ct][v] + bv;
                }
            }
        }
    }
}

// ---------- layer-1 aggregation: one wave per T2 slot, registers only ----------
__global__ __launch_bounds__(256)
void k_agg1(const int* __restrict__ ctr, const int* __restrict__ rev_t2,
            const int* __restrict__ ptr1, const int* __restrict__ cnt,
            const int* __restrict__ csr1, const float* __restrict__ dinv,
            const float* __restrict__ h1, const float* __restrict__ b1,
            float* __restrict__ x1c) {
    const int nt2 = ctr[0];
    const int lane = threadIdx.x & 63;
    const int col = lane << 1;
    const int wslot0 = (blockIdx.x * blockDim.x + threadIdx.x) >> 6;
    const int nwaves = (gridDim.x * blockDim.x) >> 6;
    for (int slot = wslot0; slot < nt2; slot += nwaves) {
        int node = rev_t2[slot];
        float dn = dinv[node];
        float dd = dn * dn;
        float2 acc = *(const float2*)&h1[((size_t)node << 7) + col];
        const float2 bb = *(const float2*)&b1[col];
        acc.x = fmaf(dd, acc.x, bb.x);
        acc.y = fmaf(dd, acc.y, bb.y);
        int j = ptr1[slot], jend = j + cnt[node];
        for (; j < jend; ++j) {
            int s = csr1[j];
            float w = dinv[s] * dn;
            const float2 h = *(const float2*)&h1[((size_t)s << 7) + col];
            acc.x = fmaf(w, h.x, acc.x);
            acc.y = fmaf(w, h.y, acc.y);
        }
        acc.x = acc.x >= 0.f ? acc.x : 0.2f * acc.x;   // fused leaky
        acc.y = acc.y >= 0.f ? acc.y : 0.2f * acc.y;
        *(float2*)&x1c[((size_t)slot << 7) + col] = acc;
    }
}

// ---------- layer-2 aggregation: one wave per S2 slot ----------
__global__ __launch_bounds__(256)
void k_agg2(const int* __restrict__ ctr, const int* __restrict__ rev_s2,
            const int* __restrict__ ptr2, const int* __restrict__ cnt,
            const int* __restrict__ csr2, const int* __restrict__ slot_t2,
            const float* __restrict__ dinv, const float* __restrict__ h2c,
            const float* __restrict__ b2, float* __restrict__ x2c) {
    const int ns2 = ctr[1];
    const int lane = threadIdx.x & 63;
    const int col = lane << 1;
    const int wslot0 = (blockIdx.x * blockDim.x + threadIdx.x) >> 6;
    const int nwaves = (gridDim.x * blockDim.x) >> 6;
    for (int slot = wslot0; slot < ns2; slot += nwaves) {
        int node = rev_s2[slot];
        float dn = dinv[node];
        float dd = dn * dn;
        float2 acc = *(const float2*)&h2c[((size_t)slot_t2[node] << 7) + col];
        const float2 bb = *(const float2*)&b2[col];
        acc.x = fmaf(dd, acc.x, bb.x);
        acc.y = fmaf(dd, acc.y, bb.y);
        int j = ptr2[slot], jend = j + cnt[node];
        for (; j < jend; ++j) {
            int s = csr2[j];
            float w = dinv[s] * dn;
            const float2 h = *(const float2*)&h2c[((size_t)slot_t2[s] << 7) + col];
            acc.x = fmaf(w, h.x, acc.x);
            acc.y = fmaf(w, h.y, acc.y);
        }
        acc.x = acc.x >= 0.f ? acc.x : 0.2f * acc.x;
        acc.y = acc.y >= 0.f ? acc.y : 0.2f * acc.y;
        *(float2*)&x2c[((size_t)slot << 7) + col] = acc;
    }
}

__global__ void k_finalA(const int* __restrict__ uidx, const int* __restrict__ slot_s2,
                         const float* __restrict__ x2c, const float* __restrict__ user_table,
                         float* __restrict__ Atmp) {
    int i = blockIdx.x * blockDim.x + threadIdx.x;
    if (i < BB * 32) {
        int b = i >> 5, q = (i & 31) << 2;
        int u = uidx[b];
        const float4 xv = *(const float4*)&x2c[((size_t)slot_s2[u] << 7) + q];
        const float4 uv = *(const float4*)&user_table[((size_t)u << 7) + q];
        float4 o;
        o.x = xv.x + uv.x; o.y = xv.y + uv.y; o.z = xv.z + uv.z; o.w = xv.w + uv.w;
        *(float4*)&Atmp[((size_t)b << 7) + q] = o;
    }
}

extern "C" void kernel_launch(void* const* d_in, const int* in_sizes, int n_in,
                              void* d_out, int out_size, void* d_ws, size_t ws_size,
                              hipStream_t stream) {
    const int*   uidx    = (const int*)d_in[0];
    const float* poi     = (const float*)d_in[1];
    const int*   src     = (const int*)d_in[2];
    const int*   dst     = ((const int*)d_in[2]) + EE;
    const float* usert   = (const float*)d_in[3];
    const float* Wp      = (const float*)d_in[4];
    const float* bp      = (const float*)d_in[5];
    const float* W1      = (const float*)d_in[6];
    const float* b1      = (const float*)d_in[7];
    const float* W2      = (const float*)d_in[8];
    const float* b2      = (const float*)d_in[9];
    const float* Wf      = (const float*)d_in[10];
    const float* bf      = (const float*)d_in[11];
    float* out = (float*)d_out;

    char* w = (char*)d_ws;
    size_t off = 0;
    auto alloc = [&](size_t bytes) -> void* {
        void* p = w + off;
        off = (off + bytes + 255) & ~(size_t)255;
        return p;
    };
    float* dinv    = (float*)alloc((size_t)NN * 4);
    int*   cnt     = (int*)  alloc((size_t)NN * 4);
    int*   mask_s2 = (int*)  alloc((size_t)NN * 4);
    int*   mask_t2 = (int*)  alloc((size_t)NN * 4);
    int*   slot_s2 = (int*)  alloc((size_t)NN * 4);
    int*   slot_t2 = (int*)  alloc((size_t)NN * 4);
    int*   rev_t2  = (int*)  alloc((size_t)NN * 4);
    int*   rev_s2  = (int*)  alloc((size_t)BB * 4);
    int*   ptr1    = (int*)  alloc((size_t)(NN + 1) * 4);
    int*   cur1    = (int*)  alloc((size_t)(NN + 1) * 4);
    int*   ptr2    = (int*)  alloc((size_t)(BB + 2) * 4);
    int*   cur2    = (int*)  alloc((size_t)(BB + 2) * 4);
    int*   ctr     = (int*)  alloc(256);
    int*   csr1    = (int*)  alloc((size_t)EE * 4);
    int*   csr2    = (int*)  alloc((size_t)EE * 4);
    float* WpW1    = (float*)alloc((size_t)320 * 128 * 4);
    float* bpW1    = (float*)alloc((size_t)128 * 4);
    ushort_t* W1Th = (ushort_t*)alloc((size_t)128 * 128 * 2);
    ushort_t* W1Tl = (ushort_t*)alloc((size_t)128 * 128 * 2);
    ushort_t* W2Th = (ushort_t*)alloc((size_t)128 * 128 * 2);
    ushort_t* W2Tl = (ushort_t*)alloc((size_t)128 * 128 * 2);
    ushort_t* WfTh = (ushort_t*)alloc((size_t)128 * 128 * 2);
    ushort_t* WfTl = (ushort_t*)alloc((size_t)128 * 128 * 2);
    ushort_t* WpTh = (ushort_t*)alloc((size_t)128 * 320 * 2);
    ushort_t* WpTl = (ushort_t*)alloc((size_t)128 * 320 * 2);
    float* h1      = (float*)alloc((size_t)NN * 128 * 4);
    float* x1c     = (float*)alloc((size_t)NN * 128 * 4);
    float* x2c     = (float*)alloc((size_t)BB * 128 * 4);
    float* Atmp    = (float*)alloc((size_t)BB * 128 * 4);
    if (off > ws_size) return;
    float* h2c = h1;

    // zero: cnt + masks (contiguous), counters
    hipMemsetAsync(cnt, 0, (size_t)((char*)slot_s2 - (char*)cnt), stream);
    hipMemsetAsync(ctr, 0, 256, stream);

    // marking + degree + dinv
    k_mark    <<<(BB + 255) / 256, 256, 0, stream>>>(uidx, mask_s2, mask_t2);
    k_deg_mark<<<2048, 256, 0, stream>>>(src, dst, mask_s2, cnt, mask_t2);
    k_dinv    <<<(NN + 255) / 256, 256, 0, stream>>>(cnt, dinv);

    // slot assignment + CSR offsets + scatter
    k_slots<<<(NN + CHUNK - 1) / CHUNK, 256, 0, stream>>>(mask_s2, mask_t2, slot_s2, slot_t2,
                                                          rev_s2, rev_t2, ctr);
    k_scan2<<<2, 1024, 0, stream>>>(ctr, rev_t2, rev_s2, cnt, ptr1, cur1, ptr2, cur2);
    k_scatter<<<2048, 256, 0, stream>>>(src, dst, mask_s2, mask_t2, slot_s2, slot_t2,
                                        cur1, cur2, csr1, csr2);

    // weight prep: split/transpose W1, W2, Wf
    k_wprepT<<<64, 256, 0, stream>>>(W1, W1Th, W1Tl, 128);
    k_wprepT<<<64, 256, 0, stream>>>(W2, W2Th, W2Tl, 128);
    k_wprepT<<<64, 256, 0, stream>>>(Wf, WfTh, WfTl, 128);

    // fused poi weights: WpW1 = Wp @ W1, bpW1 = bp @ W1; then split/transpose
    gemm_mfma<<<5, 256, 0, stream>>>(Wp, W1Th, W1Tl, nullptr, WpW1, 320, nullptr, 128);
    k_bpw1<<<1, 128, 0, stream>>>(bp, W1, bpW1);
    k_wprepT<<<160, 256, 0, stream>>>(WpW1, WpTh, WpTl, 320);

    // h1 for all nodes
    gemm_mfma<<<(NUSERS + 63) / 64, 256, 0, stream>>>(usert, W1Th, W1Tl, nullptr, h1,
                                                      NUSERS, nullptr, 128);
    gemm_mfma<<<(NPOIS + 63) / 64, 256, 0, stream>>>(poi, WpTh, WpTl, bpW1,
                                                     h1 + (size_t)NUSERS * 128,
                                                     NPOIS, nullptr, 320);

    // layer 1 at T2 (fused init + aggregate + bias + leaky)
    k_agg1<<<2048, 256, 0, stream>>>(ctr, rev_t2, ptr1, cnt, csr1, dinv, h1, b1, x1c);

    // h2 at T2 (compact GEMM, dynamic M)
    gemm_mfma<<<256, 256, 0, stream>>>(x1c, W2Th, W2Tl, nullptr, h2c, 0, ctr + 0, 128);

    // layer 2 at S2 (fused)
    k_agg2<<<256, 256, 0, stream>>>(ctr, rev_s2, ptr2, cnt, csr2, slot_t2, dinv, h2c, b2, x2c);

    // final: out = (x2[user] + user_table[user]) @ Wf + bf
    k_finalA<<<(BB * 32 + 255) / 256, 256, 0, stream>>>(uidx, slot_s2, x2c, usert, Atmp);
    gemm_mfma<<<(BB + 63) / 64, 256, 0, stream>>>(Atmp, WfTh, WfTl, bf, out, BB, nullptr, 128);
}